// Round 3
// baseline (604.192 us; speedup 1.0000x reference)
//
#include <hip/hip_runtime.h>
#include <hip/hip_bf16.h>

#define NN 8192
#define DD 128

typedef __attribute__((ext_vector_type(8))) short short8;
typedef __attribute__((ext_vector_type(4))) float f32x4;

__device__ __forceinline__ ushort f2bf(float f) {
    __hip_bfloat16 h = __float2bfloat16(f);
    return *(ushort*)&h;
}

// K1: Wh = X @ Ws  (fp32 in, f32 out)  [8192x128] = [8192x128]@[128x128]
__global__ void k1_gemm(const float* __restrict__ X, const float* __restrict__ Ws,
                        float* __restrict__ Wh) {
    int idx = blockIdx.x * 256 + threadIdx.x;   // 1M threads, one per output elem
    int r = idx >> 7, n = idx & 127;
    const float* xr = X + r * 128;
    float acc = 0.f;
#pragma unroll 8
    for (int k = 0; k < 128; k += 4) {
        float4 xv = *(const float4*)(xr + k);
        acc += xv.x * Ws[(k+0)*128 + n];
        acc += xv.y * Ws[(k+1)*128 + n];
        acc += xv.z * Ws[(k+2)*128 + n];
        acc += xv.w * Ws[(k+3)*128 + n];
    }
    Wh[idx] = acc;
}

// K2: per-row scalars + bf16 transpose. One wave per row.
__global__ void k2_prep(const float* __restrict__ Wh, const float* __restrict__ a,
                        ushort* __restrict__ WhT, float* __restrict__ C1,
                        float* __restrict__ C1s, float* __restrict__ Th,
                        float* __restrict__ E2p, float* __restrict__ E2n) {
    int wave = threadIdx.x >> 6, lane = threadIdx.x & 63;
    int i = blockIdx.x * 4 + wave;
    int d = lane * 2;
    float wh0 = Wh[i * 128 + d], wh1 = Wh[i * 128 + d + 1];
    float s1 = wh0 * a[d]       + wh1 * a[d + 1];
    float s2 = wh0 * a[128 + d] + wh1 * a[128 + d + 1];
    for (int off = 32; off; off >>= 1) {
        s1 += __shfl_xor(s1, off);
        s2 += __shfl_xor(s2, off);
    }
    WhT[(size_t)d * NN + i]       = f2bf(wh0);
    WhT[(size_t)(d + 1) * NN + i] = f2bf(wh1);
    if (lane == 0) {
        C1[i]  = __expf(s1);
        C1s[i] = __expf(0.2f * s1);
        Th[i]  = __expf(-s1);
        E2p[i] = __expf(s2);
        E2n[i] = __expf(0.2f * s2);
    }
}

// K3: masked-softmax GEMM. grid (128 row-blocks, 4 K-splits) x 256 thr.
// wave w owns rows i0+16w..+15 (full D=128 cols); P-fragments generated in
// registers directly in the MFMA A-operand layout; B-frags direct from WhT.
// exp identity: exp(leaky(s1+s2)) = s1+s2>0 ? e^{s1}e^{s2} : e^{.2s1}e^{.2s2};
// sign test via precomputed exp(-s1): no transcendentals in the hot loop.
__global__ __launch_bounds__(256) void k3_main(
    const int* __restrict__ A, const ushort* __restrict__ WhT,
    const float* __restrict__ C1, const float* __restrict__ C1s,
    const float* __restrict__ Th, const float* __restrict__ E2p,
    const float* __restrict__ E2n, float* __restrict__ Hp, float* __restrict__ Lp) {
    int lane = threadIdx.x & 63;
    int wave = threadIdx.x >> 6;
    int i0 = blockIdx.x * 64 + wave * 16;
    int kb = blockIdx.y;
    int row = i0 + (lane & 15);
    int kg = lane >> 4;                       // 0..3 quad group
    float c1 = C1[row], c1s = C1s[row], th = Th[row];
    const int* Arow = A + (size_t)row * NN;
    const ushort* Brow = WhT + (size_t)(lane & 15) * NN;
    f32x4 acc[8];
#pragma unroll
    for (int cc = 0; cc < 8; cc++) acc[cc] = (f32x4){0.f, 0.f, 0.f, 0.f};
    float lsum = 0.f;
    int kend = kb * 2048 + 2048;
    for (int k = kb * 2048 + kg * 8; k < kend; k += 32) {
        int4 a0 = *(const int4*)(Arow + k);
        int4 a1 = *(const int4*)(Arow + k + 4);
        float4 p0 = *(const float4*)(E2p + k);
        float4 p1 = *(const float4*)(E2p + k + 4);
        float4 n0 = *(const float4*)(E2n + k);
        float4 n1 = *(const float4*)(E2n + k + 4);
        int am[8]; float ep[8], en[8];
        *(int4*)(am)     = a0; *(int4*)(am + 4)   = a1;
        *(float4*)(ep)   = p0; *(float4*)(ep + 4) = p1;
        *(float4*)(en)   = n0; *(float4*)(en + 4) = n1;
        short8 af;
#pragma unroll
        for (int t = 0; t < 8; t++) {
            float w = (ep[t] > th) ? (c1 * ep[t]) : (c1s * en[t]);
            w = am[t] ? w : 0.f;
            lsum += w;
            af[t] = (short)f2bf(w);
        }
#pragma unroll
        for (int cc = 0; cc < 8; cc++) {
            short8 bf = *(const short8*)(Brow + (size_t)cc * 16 * NN + k);
            acc[cc] = __builtin_amdgcn_mfma_f32_16x16x32_bf16(af, bf, acc[cc], 0, 0, 0);
        }
    }
    // row-sum reduce across the 4 quad groups (lanes l, l^16, l^32, l^48 share a row)
    lsum += __shfl_xor(lsum, 16);
    lsum += __shfl_xor(lsum, 32);
    if (lane < 16) Lp[(size_t)kb * NN + row] = lsum;
    // C/D layout: col = lane&15, row = quad*4 + reg  [m89-verified]
    float* Hbase = Hp + ((size_t)kb * NN + i0) * DD;
#pragma unroll
    for (int cc = 0; cc < 8; cc++) {
#pragma unroll
        for (int r = 0; r < 4; r++) {
            int orow = kg * 4 + r;
            Hbase[(size_t)orow * DD + cc * 16 + (lane & 15)] = acc[cc][r];
        }
    }
}

// K4: combine split-K partials, normalize, emit fp32 (reference output dtype)
__global__ void k4_final(const float* __restrict__ Hp, const float* __restrict__ Lp,
                         float* __restrict__ out) {
    int idx = blockIdx.x * 256 + threadIdx.x;   // 1M elements
    int i = idx >> 7;
    float s = Hp[idx] + Hp[1048576 + idx] + Hp[2097152 + idx] + Hp[3145728 + idx];
    float l = Lp[i] + Lp[8192 + i] + Lp[16384 + i] + Lp[24576 + i];
    out[idx] = s / l;
}

extern "C" void kernel_launch(void* const* d_in, const int* in_sizes, int n_in,
                              void* d_out, int out_size, void* d_ws, size_t ws_size,
                              hipStream_t stream) {
    const int*   A  = (const int*)d_in[0];
    const float* X  = (const float*)d_in[1];   // fp32 per reference
    const float* Ws = (const float*)d_in[2];   // fp32
    const float* a  = (const float*)d_in[3];   // fp32
    float* out = (float*)d_out;                // fp32 output (reference dtype)

    char* ws = (char*)d_ws;
    float*  Wh  = (float*)(ws);                          // 4 MB
    ushort* WhT = (ushort*)(ws + (4u << 20));            // 2 MB
    float*  C1  = (float*)(ws + (6u << 20));             // 32 KB each
    float*  C1s = (float*)(ws + (6u << 20) + (32u << 10));
    float*  Th  = (float*)(ws + (6u << 20) + (64u << 10));
    float*  E2p = (float*)(ws + (6u << 20) + (96u << 10));
    float*  E2n = (float*)(ws + (6u << 20) + (128u << 10));
    float*  Hp  = (float*)(ws + (8u << 20));             // 16 MB (4 x N x D f32)
    float*  Lp  = (float*)(ws + (24u << 20));            // 128 KB

    k1_gemm<<<4096, 256, 0, stream>>>(X, Ws, Wh);
    k2_prep<<<2048, 256, 0, stream>>>(Wh, a, WhT, C1, C1s, Th, E2p, E2n);
    k3_main<<<dim3(128, 4), 256, 0, stream>>>(A, WhT, C1, C1s, Th, E2p, E2n, Hp, Lp);
    k4_final<<<4096, 256, 0, stream>>>(Hp, Lp, out);
}

// Round 4
// 473.907 us; speedup vs baseline: 1.2749x; 1.2749x over previous
//
#include <hip/hip_runtime.h>
#include <hip/hip_bf16.h>

#define NN 8192
#define DD 128

typedef __attribute__((ext_vector_type(8))) short short8;
typedef __attribute__((ext_vector_type(4))) float f32x4;
typedef unsigned int u32;

__device__ __forceinline__ ushort f2bf(float f) {
    __hip_bfloat16 h = __float2bfloat16(f);
    return *(ushort*)&h;
}

// async 16B/lane global->LDS. LDS dest is wave-uniform base + lane*16 (m104).
__device__ __forceinline__ void async_ld16(const void* g, void* l) {
    __builtin_amdgcn_global_load_lds(
        (const __attribute__((address_space(1))) u32*)g,
        (__attribute__((address_space(3))) u32*)l, 16, 0, 0);
}

// K1: Wh = X @ Ws (fp32). 256 blocks x 128 thr; 32 rows/block; 4x8 reg tile.
__global__ __launch_bounds__(128) void k1_gemm(const float* __restrict__ X,
                                               const float* __restrict__ Ws,
                                               float* __restrict__ Wh) {
    __shared__ float lWs[128 * 128];     // [k][n], 64 KB
    __shared__ float lX[32 * 129];       // [r][k] pad 129 (bank spread)
    int t = threadIdx.x, bx = blockIdx.x;
    const float4* Ws4 = (const float4*)Ws;
    float4* lWs4 = (float4*)lWs;
#pragma unroll
    for (int j = 0; j < 32; ++j) lWs4[t + j * 128] = Ws4[t + j * 128];
#pragma unroll
    for (int j = 0; j < 32; ++j) {
        int u = t + j * 128;
        int r = u >> 7, c = u & 127;
        lX[r * 129 + c] = X[(bx * 32 + r) * 128 + c];
    }
    __syncthreads();
    int tr = t >> 4, c = t & 15;
    int r0 = tr * 4;
    float acc[4][8];
#pragma unroll
    for (int i = 0; i < 4; ++i)
#pragma unroll
        for (int j = 0; j < 8; ++j) acc[i][j] = 0.f;
#pragma unroll 4
    for (int k = 0; k < 128; ++k) {
        float x0 = lX[(r0 + 0) * 129 + k];
        float x1 = lX[(r0 + 1) * 129 + k];
        float x2 = lX[(r0 + 2) * 129 + k];
        float x3 = lX[(r0 + 3) * 129 + k];
        float4 w0 = *(const float4*)&lWs[k * 128 + c * 8];
        float4 w1 = *(const float4*)&lWs[k * 128 + c * 8 + 4];
        float wv[8];
        *(float4*)(wv) = w0; *(float4*)(wv + 4) = w1;
#pragma unroll
        for (int j = 0; j < 8; ++j) {
            acc[0][j] += x0 * wv[j];
            acc[1][j] += x1 * wv[j];
            acc[2][j] += x2 * wv[j];
            acc[3][j] += x3 * wv[j];
        }
    }
#pragma unroll
    for (int i = 0; i < 4; ++i) {
        float4* o = (float4*)&Wh[(size_t)(bx * 32 + r0 + i) * 128 + c * 8];
        o[0] = (float4){acc[i][0], acc[i][1], acc[i][2], acc[i][3]};
        o[1] = (float4){acc[i][4], acc[i][5], acc[i][6], acc[i][7]};
    }
}

// K2: per-row scalars + bf16 transpose. One wave per row.
__global__ void k2_prep(const float* __restrict__ Wh, const float* __restrict__ a,
                        ushort* __restrict__ WhT, float* __restrict__ C1,
                        float* __restrict__ C1s, float* __restrict__ E2p,
                        float* __restrict__ E2n) {
    int wave = threadIdx.x >> 6, lane = threadIdx.x & 63;
    int i = blockIdx.x * 4 + wave;
    int d = lane * 2;
    float wh0 = Wh[i * 128 + d], wh1 = Wh[i * 128 + d + 1];
    float s1 = wh0 * a[d]       + wh1 * a[d + 1];
    float s2 = wh0 * a[128 + d] + wh1 * a[128 + d + 1];
    for (int off = 32; off; off >>= 1) {
        s1 += __shfl_xor(s1, off);
        s2 += __shfl_xor(s2, off);
    }
    WhT[(size_t)d * NN + i]       = f2bf(wh0);
    WhT[(size_t)(d + 1) * NN + i] = f2bf(wh1);
    if (lane == 0) {
        C1[i]  = __expf(s1);
        C1s[i] = __expf(0.2f * s1);
        E2p[i] = __expf(s2);
        E2n[i] = __expf(0.2f * s2);
    }
}

// K3: masked-softmax GEMM. grid(128 rowblocks, 4 ksplit) x 1024 thr (16 waves).
// wave wv: g=wv&3 row-group (16 rows), s=(wv>>2)&1 k-half, h=wv>>3 col-half.
// B-tiles (WhT k-chunk) staged via global_load_lds, shared by 8 waves each;
// frag reads are linear ds_read_b128 (conflict-free). P-fragments generated
// in registers in MFMA A-layout. exp(leaky(s1+s2)) = max(e^s1 e^s2, e^.2s1 e^.2s2).
__global__ __launch_bounds__(1024, 8) void k3_main(
    const int* __restrict__ A, const ushort* __restrict__ WhT,
    const float* __restrict__ C1, const float* __restrict__ C1s,
    const float* __restrict__ E2p, const float* __restrict__ E2n,
    float* __restrict__ Hp, float* __restrict__ Lp) {

    __shared__ __align__(16) char tile[2][8192];   // [s][cc*1024 + lane*16]
    __shared__ float red[4][16][128];              // 32 KB reduce buffer
    __shared__ float lsq[2][64];

    int tid = threadIdx.x;
    int lane = tid & 63;
    int wv = tid >> 6;
    int g = wv & 3;            // row-group
    int s = (wv >> 2) & 1;     // k-half within block
    int h = wv >> 3;           // col-half (cc = 4h..4h+3)
    int n = lane & 15;
    int kg = lane >> 4;

    int bx = blockIdx.x;
    int kb = blockIdx.y;
    int row = bx * 64 + g * 16 + n;
    int kbase = kb * 2048 + s * 1024;

    float c1 = C1[row], c1s = C1s[row];
    const int* Arow = A + (size_t)row * NN + kbase + kg * 8;
    const float* Ep = E2p + kbase + kg * 8;
    const float* En = E2n + kbase + kg * 8;
    // loader: this wave stages cc_l = h*4+g of tile[s]
    const ushort* src0 = WhT + (size_t)(h * 64 + g * 16 + n) * NN + kbase + kg * 8;
    char* dst0 = &tile[s][(h * 4 + g) * 1024 + lane * 16];

    f32x4 acc[4];
#pragma unroll
    for (int cc = 0; cc < 4; ++cc) acc[cc] = (f32x4){0.f, 0.f, 0.f, 0.f};
    float lsum = 0.f;

    for (int t = 0; t < 32; ++t) {
        int k = t * 32;
        async_ld16(src0 + k, dst0);
        int4 a0 = *(const int4*)(Arow + k);
        int4 a1 = *(const int4*)(Arow + k + 4);
        float4 pa = *(const float4*)(Ep + k);
        float4 pb = *(const float4*)(Ep + k + 4);
        float4 na = *(const float4*)(En + k);
        float4 nb = *(const float4*)(En + k + 4);
        __syncthreads();   // staging + reg loads drained (compiler vmcnt0)
        int am[8]; float ep[8], en[8];
        *(int4*)(am) = a0;       *(int4*)(am + 4) = a1;
        *(float4*)(ep) = pa;     *(float4*)(ep + 4) = pb;
        *(float4*)(en) = na;     *(float4*)(en + 4) = nb;
        short8 af;
#pragma unroll
        for (int u = 0; u < 8; ++u) {
            float w = fmaxf(c1 * ep[u], c1s * en[u]);  // exp(leaky) identity
            w = am[u] ? w : 0.f;
            lsum += w;
            af[u] = (short)f2bf(w);
        }
#pragma unroll
        for (int cc = 0; cc < 4; ++cc) {
            short8 bf = *(const short8*)&tile[s][(h * 4 + cc) * 1024 + lane * 16];
            acc[cc] = __builtin_amdgcn_mfma_f32_16x16x32_bf16(af, bf, acc[cc], 0, 0, 0);
        }
        __syncthreads();   // tile consumed before next overwrite
    }

    // row sums: lanes l, l^16, l^32, l^48 share a row
    lsum += __shfl_xor(lsum, 16);
    lsum += __shfl_xor(lsum, 32);

    // in-block reduce over s (C/D layout: col=lane&15, row=kg*4+reg  [m89])
    if (s == 0) {
#pragma unroll
        for (int cc = 0; cc < 4; ++cc)
#pragma unroll
            for (int r = 0; r < 4; ++r)
                red[g][kg * 4 + r][h * 64 + cc * 16 + n] = acc[cc][r];
        if (h == 0 && lane < 16) lsq[0][g * 16 + lane] = lsum;
    }
    __syncthreads();
    if (s == 1) {
#pragma unroll
        for (int cc = 0; cc < 4; ++cc)
#pragma unroll
            for (int r = 0; r < 4; ++r)
                red[g][kg * 4 + r][h * 64 + cc * 16 + n] += acc[cc][r];
        if (h == 0 && lane < 16) lsq[1][g * 16 + lane] = lsum;
    }
    __syncthreads();

    float* Hpb = Hp + (size_t)kb * (NN * DD) + (size_t)bx * 64 * 128;
    const float* redf = &red[0][0][0];
#pragma unroll
    for (int u = 0; u < 8; ++u) Hpb[tid + u * 1024] = redf[tid + u * 1024];
    if (tid < 64) Lp[kb * NN + bx * 64 + tid] = lsq[0][tid] + lsq[1][tid];
}

// K4: combine 4 split-K partials, normalize, emit fp32
__global__ void k4_final(const float* __restrict__ Hp, const float* __restrict__ Lp,
                         float* __restrict__ out) {
    int idx = blockIdx.x * 256 + threadIdx.x;
    int i = idx >> 7;
    float sv = Hp[idx] + Hp[1048576 + idx] + Hp[2097152 + idx] + Hp[3145728 + idx];
    float l = Lp[i] + Lp[8192 + i] + Lp[16384 + i] + Lp[24576 + i];
    out[idx] = sv / l;
}

extern "C" void kernel_launch(void* const* d_in, const int* in_sizes, int n_in,
                              void* d_out, int out_size, void* d_ws, size_t ws_size,
                              hipStream_t stream) {
    const int*   A  = (const int*)d_in[0];
    const float* X  = (const float*)d_in[1];
    const float* Ws = (const float*)d_in[2];
    const float* a  = (const float*)d_in[3];
    float* out = (float*)d_out;

    char* ws = (char*)d_ws;
    float*  Wh  = (float*)(ws);                          // 4 MB
    ushort* WhT = (ushort*)(ws + (4u << 20));            // 2 MB
    float*  C1  = (float*)(ws + (6u << 20));
    float*  C1s = (float*)(ws + (6u << 20) + (32u << 10));
    float*  E2p = (float*)(ws + (6u << 20) + (96u << 10));
    float*  E2n = (float*)(ws + (6u << 20) + (128u << 10));
    float*  Hp  = (float*)(ws + (8u << 20));             // 16 MB (4 partials)
    float*  Lp  = (float*)(ws + (24u << 20));            // 128 KB

    k1_gemm<<<256, 128, 0, stream>>>(X, Ws, Wh);
    k2_prep<<<2048, 256, 0, stream>>>(Wh, a, WhT, C1, C1s, E2p, E2n);
    k3_main<<<dim3(128, 4), 1024, 0, stream>>>(A, WhT, C1, C1s, E2p, E2n, Hp, Lp);
    k4_final<<<4096, 256, 0, stream>>>(Hp, Lp, out);
}

// Round 5
// 462.267 us; speedup vs baseline: 1.3070x; 1.0252x over previous
//
#include <hip/hip_runtime.h>
#include <hip/hip_bf16.h>

#define NN 8192
#define DD 128

typedef __attribute__((ext_vector_type(8))) short short8;
typedef __attribute__((ext_vector_type(4))) float f32x4;
typedef unsigned int u32;

__device__ __forceinline__ ushort f2bf(float f) {
    __hip_bfloat16 h = __float2bfloat16(f);
    return *(ushort*)&h;
}

// async 16B/lane global->LDS; LDS dest must be wave-uniform base + lane*16.
__device__ __forceinline__ void async_ld16(const void* g, void* l) {
    __builtin_amdgcn_global_load_lds(
        (const __attribute__((address_space(1))) u32*)g,
        (__attribute__((address_space(3))) u32*)l, 16, 0, 0);
}

// ---------------- K1: Wh = X @ Ws (fp32) ----------------
// 256 blocks x 256 thr; 32 rows/block; 4x4 register tile per thread.
__global__ __launch_bounds__(256) void k1_gemm(const float* __restrict__ X,
                                               const float* __restrict__ Ws,
                                               float* __restrict__ Wh) {
    __shared__ float lWs[128 * 132];   // [k][c] pad 132
    __shared__ float lX[32 * 132];     // [r][c] pad 132
    int t = threadIdx.x, bx = blockIdx.x;
    const float4* Ws4 = (const float4*)Ws;
    const float4* X4 = (const float4*)X;
    for (int j = 0; j < 16; ++j) {
        int u = j * 256 + t;           // 0..4095 float4s of Ws
        int k = u >> 5, c4 = u & 31;
        *(float4*)&lWs[k * 132 + c4 * 4] = Ws4[u];
    }
    for (int j = 0; j < 4; ++j) {
        int u = j * 256 + t;           // 0..1023 float4s of X tile
        int r = u >> 5, c4 = u & 31;
        *(float4*)&lX[r * 132 + c4 * 4] = X4[bx * 1024 + u];
    }
    __syncthreads();
    int r0 = (t >> 5) * 4, c0 = (t & 31) * 4;
    float acc[4][4];
#pragma unroll
    for (int i = 0; i < 4; ++i)
#pragma unroll
        for (int j = 0; j < 4; ++j) acc[i][j] = 0.f;
#pragma unroll 4
    for (int k = 0; k < 128; ++k) {
        float4 wv = *(const float4*)&lWs[k * 132 + c0];
        float x0 = lX[(r0 + 0) * 132 + k];
        float x1 = lX[(r0 + 1) * 132 + k];
        float x2 = lX[(r0 + 2) * 132 + k];
        float x3 = lX[(r0 + 3) * 132 + k];
#pragma unroll
        for (int j = 0; j < 4; ++j) {
            acc[0][j] += x0 * ((const float*)&wv)[j];
            acc[1][j] += x1 * ((const float*)&wv)[j];
            acc[2][j] += x2 * ((const float*)&wv)[j];
            acc[3][j] += x3 * ((const float*)&wv)[j];
        }
    }
#pragma unroll
    for (int i = 0; i < 4; ++i)
        *(float4*)&Wh[(size_t)(bx * 32 + r0 + i) * 128 + c0] =
            (float4){acc[i][0], acc[i][1], acc[i][2], acc[i][3]};
}

// ---------------- K2: per-row scalars + coalesced bf16 transpose ----------------
// 128 blocks x 256 thr; 64 rows/block. Transpose via LDS; each thread writes
// 64 B contiguous to WhT (no RMW write amplification).
__global__ __launch_bounds__(256) void k2_prep(const float* __restrict__ Wh,
                                               const float* __restrict__ a,
                                               ushort* __restrict__ WhT,
                                               float* __restrict__ C1,
                                               float* __restrict__ C1s,
                                               float* __restrict__ E2p,
                                               float* __restrict__ E2n) {
    __shared__ float lT[128 * 65];     // [d][r] pad 65
    __shared__ float la[256];
    int t = threadIdx.x;
    int i0 = blockIdx.x * 64;
    la[t] = a[t];
    for (int j = 0; j < 32; ++j) {
        int u = j * 256 + t;           // 0..8191
        int r = u >> 7, c = u & 127;
        lT[c * 65 + r] = Wh[(size_t)(i0 + r) * 128 + c];
    }
    __syncthreads();
    // s1/s2: 4 threads per row
    int r = t >> 2, q = t & 3;
    float s1 = 0.f, s2 = 0.f;
    for (int j = 0; j < 32; ++j) {
        int d = q * 32 + j;
        float v = lT[d * 65 + r];
        s1 += v * la[d];
        s2 += v * la[128 + d];
    }
    s1 += __shfl_xor(s1, 1); s1 += __shfl_xor(s1, 2);
    s2 += __shfl_xor(s2, 1); s2 += __shfl_xor(s2, 2);
    if (q == 0) {
        int i = i0 + r;
        C1[i]  = __expf(s1);
        C1s[i] = __expf(0.2f * s1);
        E2p[i] = __expf(s2);
        E2n[i] = __expf(0.2f * s2);
    }
    // WhT: thread t -> d=t>>1, half=t&1; 32 contiguous ushorts (64 B)
    int d = t >> 1, hf = t & 1;
    __attribute__((aligned(16))) ushort tmp[32];
#pragma unroll
    for (int s = 0; s < 32; ++s) tmp[s] = f2bf(lT[d * 65 + hf * 32 + s]);
    uint4* dst = (uint4*)&WhT[(size_t)d * NN + i0 + hf * 32];
    const uint4* srcv = (const uint4*)tmp;
#pragma unroll
    for (int s = 0; s < 4; ++s) dst[s] = srcv[s];
}

// ---------------- K3: masked-softmax GEMM ----------------
// grid (128 rowblocks, 4 ksplit) x 1024 thr (16 waves: g=wv&3 rowgroup,
// h=wv>>2 col-quarter). k128 outer tiles; A and B DMA-staged (global_load_lds)
// into double-buffered LDS; ONE barrier per outer tile. Row sums via MFMA
// against an all-ones B-frag. exp(leaky(s1+s2)) = max(e^s1 e^s2, e^.2s1 e^.2s2).
__global__ __launch_bounds__(1024, 4) void k3_main(
    const int* __restrict__ A, const ushort* __restrict__ WhT,
    const float* __restrict__ C1, const float* __restrict__ C1s,
    const float* __restrict__ E2p, const float* __restrict__ E2n,
    float* __restrict__ Hp, float* __restrict__ Lp) {

    __shared__ __align__(16) char lB[2 * 32768];   // [buf][(t'*8+cc)*1024 + lane*16]
    __shared__ __align__(16) char lA[2 * 32768];   // [buf][(g*8+t'*2+q)*1024 + lane*16]

    int tid = threadIdx.x;
    int lane = tid & 63;
    int wv = tid >> 6;
    int g = wv & 3;            // row-group (16 rows)
    int h = wv >> 2;           // col-quarter (cc = 2h, 2h+1)
    int n = lane & 15;
    int kg = lane >> 4;

    int bx = blockIdx.x;
    int kb = blockIdx.y;
    int row = bx * 64 + g * 16 + n;

    float c1 = C1[row], c1s = C1s[row];

    // staging assignments (wave-uniform): this wave stages B pairs {2wv,2wv+1}
    // and A regions {2wv,2wv+1} per outer tile.
    int p0 = wv * 2;
    int tp0 = p0 >> 3, cp0 = p0 & 7;
    int tp1 = (p0 + 1) >> 3, cp1 = (p0 + 1) & 7;
    int ga0 = p0 >> 3, ta0 = (p0 >> 1) & 3, qa0 = p0 & 1;
    int ga1 = (p0 + 1) >> 3, ta1 = ((p0 + 1) >> 1) & 3, qa1 = (p0 + 1) & 1;

    const ushort* srcB0 = WhT + (size_t)(cp0 * 16 + n) * NN + tp0 * 32 + kg * 8;
    const ushort* srcB1 = WhT + (size_t)(cp1 * 16 + n) * NN + tp1 * 32 + kg * 8;
    const int* srcA0 = A + (size_t)(bx * 64 + ga0 * 16 + n) * NN + ta0 * 32 + kg * 8 + qa0 * 4;
    const int* srcA1 = A + (size_t)(bx * 64 + ga1 * 16 + n) * NN + ta1 * 32 + kg * 8 + qa1 * 4;
    char* dstB0 = lB + p0 * 1024 + lane * 16;
    char* dstB1 = lB + (p0 + 1) * 1024 + lane * 16;
    char* dstA0 = lA + p0 * 1024 + lane * 16;
    char* dstA1 = lA + (p0 + 1) * 1024 + lane * 16;

    const size_t kbase = (size_t)kb * 2048;

    short8 ones;
#pragma unroll
    for (int j = 0; j < 8; ++j) ones[j] = (short)0x3F80;   // bf16 1.0

    f32x4 acc0 = (f32x4){0.f, 0.f, 0.f, 0.f};
    f32x4 acc1 = (f32x4){0.f, 0.f, 0.f, 0.f};
    f32x4 accl = (f32x4){0.f, 0.f, 0.f, 0.f};

    // prologue: stage tile 0 into buf 0
    {
        size_t k0 = kbase;
        async_ld16(srcB0 + k0, dstB0);
        async_ld16(srcB1 + k0, dstB1);
        async_ld16(srcA0 + k0, dstA0);
        async_ld16(srcA1 + k0, dstA1);
    }
    __syncthreads();

    for (int kt = 0; kt < 16; ++kt) {
        int b = kt & 1;
        if (kt < 15) {   // stage next tile into other buffer (drained by end barrier)
            size_t kn = kbase + (kt + 1) * 128;
            int bo = (b ^ 1) * 32768;
            async_ld16(srcB0 + kn, dstB0 + bo);
            async_ld16(srcB1 + kn, dstB1 + bo);
            async_ld16(srcA0 + kn, dstA0 + bo);
            async_ld16(srcA1 + kn, dstA1 + bo);
        }
        const char* bufA = lA + b * 32768;
        const char* bufB = lB + b * 32768;
#pragma unroll
        for (int tp = 0; tp < 4; ++tp) {
            const int4* areg = (const int4*)(bufA + (g * 8 + tp * 2) * 1024);
            int4 a0 = areg[lane];
            int4 a1 = areg[64 + lane];
            int kgl = (int)kbase + kt * 128 + tp * 32 + kg * 8;
            float4 pa = *(const float4*)(E2p + kgl);
            float4 pb = *(const float4*)(E2p + kgl + 4);
            float4 na = *(const float4*)(E2n + kgl);
            float4 nb = *(const float4*)(E2n + kgl + 4);
            int am[8]; float ep[8], en[8];
            *(int4*)(am) = a0;     *(int4*)(am + 4) = a1;
            *(float4*)(ep) = pa;   *(float4*)(ep + 4) = pb;
            *(float4*)(en) = na;   *(float4*)(en + 4) = nb;
            short8 af;
#pragma unroll
            for (int u = 0; u < 8; ++u) {
                float w = fmaxf(c1 * ep[u], c1s * en[u]);
                w = am[u] ? w : 0.f;
                af[u] = (short)f2bf(w);
            }
            const short8* bb = (const short8*)(bufB + tp * 8192);
            acc0 = __builtin_amdgcn_mfma_f32_16x16x32_bf16(af, bb[(2 * h + 0) * 64 + lane], acc0, 0, 0, 0);
            acc1 = __builtin_amdgcn_mfma_f32_16x16x32_bf16(af, bb[(2 * h + 1) * 64 + lane], acc1, 0, 0, 0);
            accl = __builtin_amdgcn_mfma_f32_16x16x32_bf16(af, ones, accl, 0, 0, 0);
        }
        __syncthreads();
    }

    // epilogue. C/D layout: col = lane&15, row = (lane>>4)*4 + reg  [m89]
    if (h == 0 && n == 0) {
#pragma unroll
        for (int r = 0; r < 4; ++r)
            Lp[(size_t)kb * NN + bx * 64 + g * 16 + kg * 4 + r] = accl[r];
    }
    float* Hpb = Hp + (size_t)kb * (NN * DD);
#pragma unroll
    for (int r = 0; r < 4; ++r) {
        int orow = bx * 64 + g * 16 + kg * 4 + r;
        Hpb[(size_t)orow * DD + h * 32 + n] = acc0[r];
        Hpb[(size_t)orow * DD + h * 32 + 16 + n] = acc1[r];
    }
}

// ---------------- K4: combine split-K partials, normalize ----------------
__global__ void k4_final(const float* __restrict__ Hp, const float* __restrict__ Lp,
                         float* __restrict__ out) {
    int idx = blockIdx.x * 256 + threadIdx.x;
    int i = idx >> 7;
    float sv = Hp[idx] + Hp[1048576 + idx] + Hp[2097152 + idx] + Hp[3145728 + idx];
    float l = Lp[i] + Lp[8192 + i] + Lp[16384 + i] + Lp[24576 + i];
    out[idx] = sv / l;
}

extern "C" void kernel_launch(void* const* d_in, const int* in_sizes, int n_in,
                              void* d_out, int out_size, void* d_ws, size_t ws_size,
                              hipStream_t stream) {
    const int*   A  = (const int*)d_in[0];
    const float* X  = (const float*)d_in[1];
    const float* Ws = (const float*)d_in[2];
    const float* a  = (const float*)d_in[3];
    float* out = (float*)d_out;

    char* ws = (char*)d_ws;
    float*  Wh  = (float*)(ws);                          // 4 MB
    ushort* WhT = (ushort*)(ws + (4u << 20));            // 2 MB
    float*  C1  = (float*)(ws + (6u << 20));
    float*  C1s = (float*)(ws + (6u << 20) + (32u << 10));
    float*  E2p = (float*)(ws + (6u << 20) + (96u << 10));
    float*  E2n = (float*)(ws + (6u << 20) + (128u << 10));
    float*  Hp  = (float*)(ws + (8u << 20));             // 16 MB (4 partials)
    float*  Lp  = (float*)(ws + (24u << 20));            // 128 KB

    k1_gemm<<<256, 256, 0, stream>>>(X, Ws, Wh);
    k2_prep<<<128, 256, 0, stream>>>(Wh, a, WhT, C1, C1s, E2p, E2n);
    k3_main<<<dim3(128, 4), 1024, 0, stream>>>(A, WhT, C1, C1s, E2p, E2n, Hp, Lp);
    k4_final<<<4096, 256, 0, stream>>>(Hp, Lp, out);
}